// Round 1
// baseline (85.641 us; speedup 1.0000x reference)
//
#include <hip/hip_runtime.h>
#include <math.h>

// DisCo (distance correlation) for N=8192, scalar output.
// Structure: O(N^2) pairwise sweeps over vector data (96KB, cache-resident).
//   K1: row means aavg[i], bavg[i]
//   K2: grand means ga, gb; in-place adj[i] = avg[i] - g/2  (A = |da| - adj_i - adj_j)
//   K3: row sums S_AB, S_AA, S_BB -> per-wave partials of num/denA/denB
//   K4: final scalar reduce + power branch + NaN/clamp
// All reductions are fixed-order (shuffle butterfly + serial) -> deterministic.

#define NN 8192
#define BLK 256
#define CHUNKS 64                      // column chunks (one wave = all 64 chunks)
#define RSLOT 4                        // row slots (waves) per block
#define RPT 4                          // rows per thread
#define ROWS_PER_BLOCK (RSLOT * RPT)   // 16
#define GRID1 (NN / ROWS_PER_BLOCK)    // 512 blocks
#define ITERS (NN / CHUNKS)            // 128 inner iterations
#define NPART (GRID1 * RSLOT)          // 2048 per-wave partials

// ---------------------------------------------------------------- K1: row means
__global__ __launch_bounds__(BLK) void k_rowmeans(
    const float* __restrict__ a, const float* __restrict__ b,
    const float* __restrict__ w,
    float* __restrict__ aavg, float* __restrict__ bavg) {
  const int c = threadIdx.x & (CHUNKS - 1);
  const int r = threadIdx.x >> 6;
  const int i0 = blockIdx.x * ROWS_PER_BLOCK + r * RPT;

  float ai[RPT], bi[RPT], sa[RPT], sb[RPT];
#pragma unroll
  for (int m = 0; m < RPT; ++m) {
    ai[m] = a[i0 + m];
    bi[m] = b[i0 + m];
    sa[m] = 0.f;
    sb[m] = 0.f;
  }

#pragma unroll 4
  for (int k = 0; k < ITERS; ++k) {
    const int j = k * CHUNKS + c;   // lanes read consecutive j -> coalesced, L1-hit
    const float aj = a[j];
    const float bj = b[j];
    const float wj = w[j];
#pragma unroll
    for (int m = 0; m < RPT; ++m) {
      sa[m] = fmaf(fabsf(ai[m] - aj), wj, sa[m]);  // abs folds to VOP3 src modifier
      sb[m] = fmaf(fabsf(bi[m] - bj), wj, sb[m]);
    }
  }

#pragma unroll
  for (int off = 32; off >= 1; off >>= 1) {
#pragma unroll
    for (int m = 0; m < RPT; ++m) {
      sa[m] += __shfl_xor(sa[m], off);
      sb[m] += __shfl_xor(sb[m], off);
    }
  }
  if (c == 0) {
#pragma unroll
    for (int m = 0; m < RPT; ++m) {
      aavg[i0 + m] = sa[m] * (1.0f / NN);
      bavg[i0 + m] = sb[m] * (1.0f / NN);
    }
  }
}

// ------------------------------------------------- K2: grand means + centering
__global__ __launch_bounds__(BLK) void k_center(
    float* __restrict__ aavg, float* __restrict__ bavg,
    const float* __restrict__ w) {
  double sa = 0.0, sb = 0.0;
  for (int k = 0; k < NN / BLK; ++k) {
    const int i = threadIdx.x + k * BLK;
    sa += (double)aavg[i] * (double)w[i];
    sb += (double)bavg[i] * (double)w[i];
  }
#pragma unroll
  for (int off = 32; off >= 1; off >>= 1) {
    sa += __shfl_xor(sa, off);
    sb += __shfl_xor(sb, off);
  }
  __shared__ double lsa[4], lsb[4];
  __shared__ float h2[2];
  const int lane = threadIdx.x & 63;
  const int wv = threadIdx.x >> 6;
  if (lane == 0) { lsa[wv] = sa; lsb[wv] = sb; }
  __syncthreads();
  if (threadIdx.x == 0) {
    const double ga = (lsa[0] + lsa[1] + lsa[2] + lsa[3]) / NN;
    const double gb = (lsb[0] + lsb[1] + lsb[2] + lsb[3]) / NN;
    h2[0] = (float)(0.5 * ga);   // adj = avg - g/2 (symmetric split)
    h2[1] = (float)(0.5 * gb);
  }
  __syncthreads();
  const float ha = h2[0], hb = h2[1];
  for (int k = 0; k < NN / BLK; ++k) {
    const int i = threadIdx.x + k * BLK;
    aavg[i] -= ha;   // each element touched by exactly one thread: no race
    bavg[i] -= hb;
  }
}

// ------------------------------------------- K3: centered row sums -> partials
__global__ __launch_bounds__(BLK) void k_pass2(
    const float* __restrict__ a, const float* __restrict__ b,
    const float* __restrict__ w,
    const float* __restrict__ adja, const float* __restrict__ adjb,
    float* __restrict__ pAB, float* __restrict__ pAA, float* __restrict__ pBB) {
  const int c = threadIdx.x & (CHUNKS - 1);
  const int r = threadIdx.x >> 6;
  const int i0 = blockIdx.x * ROWS_PER_BLOCK + r * RPT;

  float ai[RPT], bi[RPT], ra[RPT], rb[RPT];
  float sAB[RPT], sAA[RPT], sBB[RPT];
#pragma unroll
  for (int m = 0; m < RPT; ++m) {
    ai[m] = a[i0 + m];
    bi[m] = b[i0 + m];
    ra[m] = adja[i0 + m];
    rb[m] = adjb[i0 + m];
    sAB[m] = 0.f; sAA[m] = 0.f; sBB[m] = 0.f;
  }

#pragma unroll 2
  for (int k = 0; k < ITERS; ++k) {
    const int j = k * CHUNKS + c;
    const float aj = a[j];
    const float bj = b[j];
    const float wj = w[j];
    const float caj = adja[j];
    const float cbj = adjb[j];
#pragma unroll
    for (int m = 0; m < RPT; ++m) {
      const float A = (fabsf(ai[m] - aj) - ra[m]) - caj;  // 3 VALU
      const float B = (fabsf(bi[m] - bj) - rb[m]) - cbj;  // 3 VALU
      const float Aw = A * wj;
      const float Bw = B * wj;
      sAB[m] = fmaf(Aw, B, sAB[m]);
      sAA[m] = fmaf(Aw, A, sAA[m]);
      sBB[m] = fmaf(Bw, B, sBB[m]);
    }
  }

#pragma unroll
  for (int off = 32; off >= 1; off >>= 1) {
#pragma unroll
    for (int m = 0; m < RPT; ++m) {
      sAB[m] += __shfl_xor(sAB[m], off);
      sAA[m] += __shfl_xor(sAA[m], off);
      sBB[m] += __shfl_xor(sBB[m], off);
    }
  }
  if (c == 0) {
    float pab = 0.f, paa = 0.f, pbb = 0.f;
#pragma unroll
    for (int m = 0; m < RPT; ++m) {
      const float wi = w[i0 + m];
      pab += fabsf(sAB[m]) * wi;   // abs of full row sum (row completes in-wave)
      paa += sAA[m] * wi;
      pbb += sBB[m] * wi;
    }
    const int widx = blockIdx.x * RSLOT + r;
    pAB[widx] = pab;
    pAA[widx] = paa;
    pBB[widx] = pbb;
  }
}

// ---------------------------------------------------------------- K4: finalize
__global__ __launch_bounds__(BLK) void k_final(
    const float* __restrict__ pAB, const float* __restrict__ pAA,
    const float* __restrict__ pBB, const int* __restrict__ powerPtr,
    float* __restrict__ out) {
  double sab = 0.0, saa = 0.0, sbb = 0.0;
  for (int k = 0; k < NPART / BLK; ++k) {
    const int i = threadIdx.x + k * BLK;
    sab += (double)pAB[i];
    saa += (double)pAA[i];
    sbb += (double)pBB[i];
  }
#pragma unroll
  for (int off = 32; off >= 1; off >>= 1) {
    sab += __shfl_xor(sab, off);
    saa += __shfl_xor(saa, off);
    sbb += __shfl_xor(sbb, off);
  }
  __shared__ double l[3][4];
  const int lane = threadIdx.x & 63;
  const int wv = threadIdx.x >> 6;
  if (lane == 0) { l[0][wv] = sab; l[1][wv] = saa; l[2][wv] = sbb; }
  __syncthreads();
  if (threadIdx.x == 0) {
    const double n2 = (double)NN * (double)NN;
    const double num = (l[0][0] + l[0][1] + l[0][2] + l[0][3]) / n2;
    const double mAA = (l[1][0] + l[1][1] + l[1][2] + l[1][3]) / n2;
    const double mBB = (l[2][0] + l[2][1] + l[2][2] + l[2][3]) / n2;
    const double den = fabs(mAA * mBB);
    const int p = powerPtr[0];
    double d;
    if (p == 1) {
      d = num / sqrt(den + 1e-12);
    } else if (p == 2) {
      d = (num * num) / (den + 1e-12);
    } else {
      d = pow(num / sqrt(mAA * mBB) + 1e-12, (double)p);
    }
    if (isnan(d)) d = 0.0;
    if (d < 0.0) d = 0.0;
    out[0] = (float)d;
  }
}

// -------------------------------------------------------------------- launcher
extern "C" void kernel_launch(void* const* d_in, const int* in_sizes, int n_in,
                              void* d_out, int out_size, void* d_ws, size_t ws_size,
                              hipStream_t stream) {
  const float* a = (const float*)d_in[0];
  const float* b = (const float*)d_in[1];
  const float* w = (const float*)d_in[2];
  const int* power = (const int*)d_in[3];
  float* out = (float*)d_out;

  float* ws = (float*)d_ws;
  float* aavg = ws;              // [NN]  -> becomes adja after k_center
  float* bavg = ws + NN;         // [NN]  -> becomes adjb
  float* pAB = ws + 2 * NN;      // [NPART]
  float* pAA = pAB + NPART;      // [NPART]
  float* pBB = pAA + NPART;      // [NPART]

  k_rowmeans<<<GRID1, BLK, 0, stream>>>(a, b, w, aavg, bavg);
  k_center<<<1, BLK, 0, stream>>>(aavg, bavg, w);
  k_pass2<<<GRID1, BLK, 0, stream>>>(a, b, w, aavg, bavg, pAB, pAA, pBB);
  k_final<<<1, BLK, 0, stream>>>(pAB, pAA, pBB, power, out);
}

// Round 2
// 47.732 us; speedup vs baseline: 1.7942x; 1.7942x over previous
//
#include <hip/hip_runtime.h>
#include <math.h>

// DisCo (distance correlation) for N=8192, scalar output.
//   K1 (pass1): per-segment partial weighted row sums of |ai-aj|, |bi-bj|
//   K2 (center): assemble row means, grand means, adj[i] = avg[i] - g/2
//   K3 (pass2): per-segment partial centered row sums S_AB, S_AA, S_BB
//   K4 (fin):   per-row assembly + abs + weight, global reduce, power branch
// All reductions fixed-order -> deterministic.

#define NN 8192
#define BLK 256
#define RPT 4                           // rows per thread
#define RSLOT 4                         // waves per block
#define ROWS_PER_BLOCK (RSLOT * RPT)    // 16
#define GRIDX (NN / ROWS_PER_BLOCK)     // 512
#define CSPLIT 4                        // column segments (occupancy x4)
#define SEGC (NN / CSPLIT)              // 2048 columns per segment
#define ITERS (SEGC / (64 * 4))         // 8 float4-iterations per segment

// ---------------------------------------------------------------- helpers
__device__ __forceinline__ void p1_elem(
    float aj, float bj, float wj,
    const float* __restrict__ ai, const float* __restrict__ bi,
    float* __restrict__ sa, float* __restrict__ sb) {
#pragma unroll
  for (int m = 0; m < RPT; ++m) {
    sa[m] = fmaf(fabsf(ai[m] - aj), wj, sa[m]);
    sb[m] = fmaf(fabsf(bi[m] - bj), wj, sb[m]);
  }
}

__device__ __forceinline__ void p2_elem(
    float aj, float bj, float wj, float caj, float cbj,
    const float* __restrict__ ai, const float* __restrict__ bi,
    const float* __restrict__ ra, const float* __restrict__ rb,
    float* __restrict__ sAB, float* __restrict__ sAA, float* __restrict__ sBB) {
#pragma unroll
  for (int m = 0; m < RPT; ++m) {
    const float A = (fabsf(ai[m] - aj) - ra[m]) - caj;
    const float B = (fabsf(bi[m] - bj) - rb[m]) - cbj;
    const float Aw = A * wj;
    const float Bw = B * wj;
    sAB[m] = fmaf(Aw, B, sAB[m]);
    sAA[m] = fmaf(Aw, A, sAA[m]);
    sBB[m] = fmaf(Bw, B, sBB[m]);
  }
}

// ---------------------------------------------------------------- K1: pass 1
__global__ __launch_bounds__(BLK) void k_pass1(
    const float* __restrict__ a, const float* __restrict__ b,
    const float* __restrict__ w,
    float* __restrict__ pa, float* __restrict__ pb) {
  const int lane = threadIdx.x & 63;
  const int wv = threadIdx.x >> 6;
  const int i0 = blockIdx.x * ROWS_PER_BLOCK + wv * RPT;
  const int seg = blockIdx.y;

  float ai[RPT], bi[RPT], sa[RPT], sb[RPT];
#pragma unroll
  for (int m = 0; m < RPT; ++m) {
    ai[m] = a[i0 + m]; bi[m] = b[i0 + m];
    sa[m] = 0.f; sb[m] = 0.f;
  }

  const int jb = seg * SEGC;
  const float4* a4 = (const float4*)(a + jb) + lane;
  const float4* b4 = (const float4*)(b + jb) + lane;
  const float4* w4 = (const float4*)(w + jb) + lane;

  float4 A0 = a4[0], B0 = b4[0], W0 = w4[0];
#pragma unroll 1
  for (int k = 0; k < ITERS - 1; ++k) {
    const int nx = (k + 1) * 64;
    const float4 A1 = a4[nx], B1 = b4[nx], W1 = w4[nx];
    p1_elem(A0.x, B0.x, W0.x, ai, bi, sa, sb);
    p1_elem(A0.y, B0.y, W0.y, ai, bi, sa, sb);
    p1_elem(A0.z, B0.z, W0.z, ai, bi, sa, sb);
    p1_elem(A0.w, B0.w, W0.w, ai, bi, sa, sb);
    A0 = A1; B0 = B1; W0 = W1;
  }
  p1_elem(A0.x, B0.x, W0.x, ai, bi, sa, sb);
  p1_elem(A0.y, B0.y, W0.y, ai, bi, sa, sb);
  p1_elem(A0.z, B0.z, W0.z, ai, bi, sa, sb);
  p1_elem(A0.w, B0.w, W0.w, ai, bi, sa, sb);

#pragma unroll
  for (int off = 32; off >= 1; off >>= 1) {
#pragma unroll
    for (int m = 0; m < RPT; ++m) {
      sa[m] += __shfl_xor(sa[m], off);
      sb[m] += __shfl_xor(sb[m], off);
    }
  }
  if (lane == 0) {
#pragma unroll
    for (int m = 0; m < RPT; ++m) {
      pa[seg * NN + i0 + m] = sa[m];
      pb[seg * NN + i0 + m] = sb[m];
    }
  }
}

// ----------------------------------------- K2: assemble row means + centering
__global__ __launch_bounds__(1024) void k_center(
    const float* __restrict__ pa, const float* __restrict__ pb,
    const float* __restrict__ w,
    float* __restrict__ adja, float* __restrict__ adjb) {
  double sa = 0.0, sb = 0.0;
  for (int k = 0; k < NN / 1024; ++k) {
    const int i = threadIdx.x + k * 1024;
    const float av = (pa[i] + pa[NN + i] + pa[2 * NN + i] + pa[3 * NN + i]) * (1.0f / NN);
    const float bv = (pb[i] + pb[NN + i] + pb[2 * NN + i] + pb[3 * NN + i]) * (1.0f / NN);
    adja[i] = av; adjb[i] = bv;
    sa += (double)av * (double)w[i];
    sb += (double)bv * (double)w[i];
  }
#pragma unroll
  for (int off = 32; off >= 1; off >>= 1) {
    sa += __shfl_xor(sa, off);
    sb += __shfl_xor(sb, off);
  }
  __shared__ double lsa[16], lsb[16];
  __shared__ float h2[2];
  const int lane = threadIdx.x & 63;
  const int wv = threadIdx.x >> 6;
  if (lane == 0) { lsa[wv] = sa; lsb[wv] = sb; }
  __syncthreads();
  if (threadIdx.x == 0) {
    double ga = 0.0, gb = 0.0;
    for (int t = 0; t < 16; ++t) { ga += lsa[t]; gb += lsb[t]; }
    h2[0] = (float)(0.5 * ga / NN);   // adj = avg - g/2 (symmetric split)
    h2[1] = (float)(0.5 * gb / NN);
  }
  __syncthreads();
  const float ha = h2[0], hb = h2[1];
  for (int k = 0; k < NN / 1024; ++k) {
    const int i = threadIdx.x + k * 1024;
    adja[i] -= ha;
    adjb[i] -= hb;
  }
}

// ---------------------------------------------------------------- K3: pass 2
__global__ __launch_bounds__(BLK) void k_pass2(
    const float* __restrict__ a, const float* __restrict__ b,
    const float* __restrict__ w,
    const float* __restrict__ adja, const float* __restrict__ adjb,
    float* __restrict__ pAB, float* __restrict__ pAA, float* __restrict__ pBB) {
  const int lane = threadIdx.x & 63;
  const int wv = threadIdx.x >> 6;
  const int i0 = blockIdx.x * ROWS_PER_BLOCK + wv * RPT;
  const int seg = blockIdx.y;

  float ai[RPT], bi[RPT], ra[RPT], rb[RPT];
  float sAB[RPT], sAA[RPT], sBB[RPT];
#pragma unroll
  for (int m = 0; m < RPT; ++m) {
    ai[m] = a[i0 + m]; bi[m] = b[i0 + m];
    ra[m] = adja[i0 + m]; rb[m] = adjb[i0 + m];
    sAB[m] = 0.f; sAA[m] = 0.f; sBB[m] = 0.f;
  }

  const int jb = seg * SEGC;
  const float4* a4  = (const float4*)(a + jb)    + lane;
  const float4* b4  = (const float4*)(b + jb)    + lane;
  const float4* w4  = (const float4*)(w + jb)    + lane;
  const float4* ca4 = (const float4*)(adja + jb) + lane;
  const float4* cb4 = (const float4*)(adjb + jb) + lane;

  float4 A0 = a4[0], B0 = b4[0], W0 = w4[0], CA0 = ca4[0], CB0 = cb4[0];
#pragma unroll 1
  for (int k = 0; k < ITERS - 1; ++k) {
    const int nx = (k + 1) * 64;
    const float4 A1 = a4[nx], B1 = b4[nx], W1 = w4[nx], CA1 = ca4[nx], CB1 = cb4[nx];
    p2_elem(A0.x, B0.x, W0.x, CA0.x, CB0.x, ai, bi, ra, rb, sAB, sAA, sBB);
    p2_elem(A0.y, B0.y, W0.y, CA0.y, CB0.y, ai, bi, ra, rb, sAB, sAA, sBB);
    p2_elem(A0.z, B0.z, W0.z, CA0.z, CB0.z, ai, bi, ra, rb, sAB, sAA, sBB);
    p2_elem(A0.w, B0.w, W0.w, CA0.w, CB0.w, ai, bi, ra, rb, sAB, sAA, sBB);
    A0 = A1; B0 = B1; W0 = W1; CA0 = CA1; CB0 = CB1;
  }
  p2_elem(A0.x, B0.x, W0.x, CA0.x, CB0.x, ai, bi, ra, rb, sAB, sAA, sBB);
  p2_elem(A0.y, B0.y, W0.y, CA0.y, CB0.y, ai, bi, ra, rb, sAB, sAA, sBB);
  p2_elem(A0.z, B0.z, W0.z, CA0.z, CB0.z, ai, bi, ra, rb, sAB, sAA, sBB);
  p2_elem(A0.w, B0.w, W0.w, CA0.w, CB0.w, ai, bi, ra, rb, sAB, sAA, sBB);

#pragma unroll
  for (int off = 32; off >= 1; off >>= 1) {
#pragma unroll
    for (int m = 0; m < RPT; ++m) {
      sAB[m] += __shfl_xor(sAB[m], off);
      sAA[m] += __shfl_xor(sAA[m], off);
      sBB[m] += __shfl_xor(sBB[m], off);
    }
  }
  if (lane == 0) {
#pragma unroll
    for (int m = 0; m < RPT; ++m) {
      pAB[seg * NN + i0 + m] = sAB[m];
      pAA[seg * NN + i0 + m] = sAA[m];
      pBB[seg * NN + i0 + m] = sBB[m];
    }
  }
}

// ------------------------------- K4: per-row assembly + final scalar reduce
__global__ __launch_bounds__(1024) void k_fin(
    const float* __restrict__ pAB, const float* __restrict__ pAA,
    const float* __restrict__ pBB, const float* __restrict__ w,
    const int* __restrict__ powerPtr, float* __restrict__ out) {
  double ab = 0.0, aa = 0.0, bb = 0.0;
  for (int k = 0; k < NN / 1024; ++k) {
    const int i = threadIdx.x + k * 1024;
    const float sab = pAB[i] + pAB[NN + i] + pAB[2 * NN + i] + pAB[3 * NN + i];
    const float saa = pAA[i] + pAA[NN + i] + pAA[2 * NN + i] + pAA[3 * NN + i];
    const float sbb = pBB[i] + pBB[NN + i] + pBB[2 * NN + i] + pBB[3 * NN + i];
    const float wi = w[i];
    ab += (double)(fabsf(sab) * wi);   // abs of full row sum
    aa += (double)(saa * wi);
    bb += (double)(sbb * wi);
  }
#pragma unroll
  for (int off = 32; off >= 1; off >>= 1) {
    ab += __shfl_xor(ab, off);
    aa += __shfl_xor(aa, off);
    bb += __shfl_xor(bb, off);
  }
  __shared__ double l[3][16];
  const int lane = threadIdx.x & 63;
  const int wv = threadIdx.x >> 6;
  if (lane == 0) { l[0][wv] = ab; l[1][wv] = aa; l[2][wv] = bb; }
  __syncthreads();
  if (threadIdx.x == 0) {
    double sab = 0.0, saa = 0.0, sbb = 0.0;
    for (int t = 0; t < 16; ++t) { sab += l[0][t]; saa += l[1][t]; sbb += l[2][t]; }
    const double n2 = (double)NN * (double)NN;
    const double num = sab / n2;
    const double mAA = saa / n2;
    const double mBB = sbb / n2;
    const double den = fabs(mAA * mBB);
    const int p = powerPtr[0];
    double d;
    if (p == 1) {
      d = num / sqrt(den + 1e-12);
    } else if (p == 2) {
      d = (num * num) / (den + 1e-12);
    } else {
      d = pow(num / sqrt(mAA * mBB) + 1e-12, (double)p);
    }
    if (isnan(d)) d = 0.0;
    if (d < 0.0) d = 0.0;
    out[0] = (float)d;
  }
}

// -------------------------------------------------------------------- launcher
extern "C" void kernel_launch(void* const* d_in, const int* in_sizes, int n_in,
                              void* d_out, int out_size, void* d_ws, size_t ws_size,
                              hipStream_t stream) {
  const float* a = (const float*)d_in[0];
  const float* b = (const float*)d_in[1];
  const float* w = (const float*)d_in[2];
  const int* power = (const int*)d_in[3];
  float* out = (float*)d_out;

  float* ws = (float*)d_ws;
  float* pa   = ws;                       // [CSPLIT*NN]
  float* pb   = pa + CSPLIT * NN;         // [CSPLIT*NN]
  float* adja = pb + CSPLIT * NN;         // [NN]
  float* adjb = adja + NN;                // [NN]
  float* pAB  = adjb + NN;                // [CSPLIT*NN]
  float* pAA  = pAB + CSPLIT * NN;        // [CSPLIT*NN]
  float* pBB  = pAA + CSPLIT * NN;        // [CSPLIT*NN]

  const dim3 grid(GRIDX, CSPLIT);
  k_pass1<<<grid, BLK, 0, stream>>>(a, b, w, pa, pb);
  k_center<<<1, 1024, 0, stream>>>(pa, pb, w, adja, adjb);
  k_pass2<<<grid, BLK, 0, stream>>>(a, b, w, adja, adjb, pAB, pAA, pBB);
  k_fin<<<1, 1024, 0, stream>>>(pAB, pAA, pBB, w, power, out);
}

// Round 3
// 43.306 us; speedup vs baseline: 1.9776x; 1.1022x over previous
//
#include <hip/hip_runtime.h>
#include <math.h>

// DisCo (distance correlation) for N=8192, scalar output. 5 kernels:
//   K1 k_pass1 (512x4): partial weighted row sums of |ai-aj|,|bi-bj| -> pa,pb[4][N]
//   K2 k_mid   (32):    avg[i] = sum_seg p / N; per-block dbl partial of sum(w*avg)
//   K3 k_pass2 (512x4): prologue reduces 32 partials -> ga/2; centered row sums
//                       with on-the-fly adj_j = avg[j]-ga/2; partials pAB/pAA/pBB
//   K4 k_tail  (32):    assemble full rows, abs(S_AB)*w_i, per-block dbl partials
//   K5 k_fin   (1x64):  reduce 32 triples, power branch, NaN/clamp
// All reductions fixed-order -> deterministic.

#define NN 8192
#define BLK 256
#define RPT 4                           // rows per thread
#define ROWS_PER_BLOCK 16               // 4 waves x RPT (waves share columns)
#define GRIDX 512                       // NN / ROWS_PER_BLOCK
#define CSPLIT 4                        // column segments
#define SEGC 2048                       // NN / CSPLIT
#define ITERS 8                         // SEGC / (64 lanes * 4 floats)
#define MIDB 32                         // glue-kernel blocks

// ---------------------------------------------------------------- helpers
__device__ __forceinline__ void p1_elem(
    float aj, float bj, float wj,
    const float* __restrict__ ai, const float* __restrict__ bi,
    float* __restrict__ sa, float* __restrict__ sb) {
#pragma unroll
  for (int m = 0; m < RPT; ++m) {
    sa[m] = fmaf(fabsf(ai[m] - aj), wj, sa[m]);
    sb[m] = fmaf(fabsf(bi[m] - bj), wj, sb[m]);
  }
}

__device__ __forceinline__ void p2_elem(
    float aj, float bj, float wj, float avgaj, float avgbj,
    float ha, float hb,
    const float* __restrict__ ai, const float* __restrict__ bi,
    const float* __restrict__ ra, const float* __restrict__ rb,
    float* __restrict__ sAB, float* __restrict__ sAA, float* __restrict__ sBB) {
  const float caj = avgaj - ha;   // adj_j^a
  const float cbj = avgbj - hb;   // adj_j^b
#pragma unroll
  for (int m = 0; m < RPT; ++m) {
    const float A = (fabsf(ai[m] - aj) - ra[m]) - caj;
    const float B = (fabsf(bi[m] - bj) - rb[m]) - cbj;
    const float Aw = A * wj;
    const float Bw = B * wj;
    sAB[m] = fmaf(Aw, B, sAB[m]);
    sAA[m] = fmaf(Aw, A, sAA[m]);
    sBB[m] = fmaf(Bw, B, sBB[m]);
  }
}

// ---------------------------------------------------------------- K1: pass 1
__global__ __launch_bounds__(BLK) void k_pass1(
    const float* __restrict__ a, const float* __restrict__ b,
    const float* __restrict__ w,
    float* __restrict__ pa, float* __restrict__ pb) {
  const int lane = threadIdx.x & 63;
  const int wv = threadIdx.x >> 6;
  const int i0 = blockIdx.x * ROWS_PER_BLOCK + wv * RPT;
  const int seg = blockIdx.y;

  float ai[RPT], bi[RPT], sa[RPT], sb[RPT];
#pragma unroll
  for (int m = 0; m < RPT; ++m) {
    ai[m] = a[i0 + m]; bi[m] = b[i0 + m];
    sa[m] = 0.f; sb[m] = 0.f;
  }

  const int jb = seg * SEGC;
  const float4* a4 = (const float4*)(a + jb) + lane;
  const float4* b4 = (const float4*)(b + jb) + lane;
  const float4* w4 = (const float4*)(w + jb) + lane;

  float4 A0 = a4[0], B0 = b4[0], W0 = w4[0];
#pragma unroll 1
  for (int k = 0; k < ITERS - 1; ++k) {
    const int nx = (k + 1) * 64;
    const float4 A1 = a4[nx], B1 = b4[nx], W1 = w4[nx];
    p1_elem(A0.x, B0.x, W0.x, ai, bi, sa, sb);
    p1_elem(A0.y, B0.y, W0.y, ai, bi, sa, sb);
    p1_elem(A0.z, B0.z, W0.z, ai, bi, sa, sb);
    p1_elem(A0.w, B0.w, W0.w, ai, bi, sa, sb);
    A0 = A1; B0 = B1; W0 = W1;
  }
  p1_elem(A0.x, B0.x, W0.x, ai, bi, sa, sb);
  p1_elem(A0.y, B0.y, W0.y, ai, bi, sa, sb);
  p1_elem(A0.z, B0.z, W0.z, ai, bi, sa, sb);
  p1_elem(A0.w, B0.w, W0.w, ai, bi, sa, sb);

#pragma unroll
  for (int off = 32; off >= 1; off >>= 1) {
#pragma unroll
    for (int m = 0; m < RPT; ++m) {
      sa[m] += __shfl_xor(sa[m], off);
      sb[m] += __shfl_xor(sb[m], off);
    }
  }
  if (lane == 0) {
#pragma unroll
    for (int m = 0; m < RPT; ++m) {
      pa[seg * NN + i0 + m] = sa[m];
      pb[seg * NN + i0 + m] = sb[m];
    }
  }
}

// ------------------------- K2: assemble row means + per-block grand partials
__global__ __launch_bounds__(BLK) void k_mid(
    const float* __restrict__ pa, const float* __restrict__ pb,
    const float* __restrict__ w,
    float* __restrict__ avga, float* __restrict__ avgb,
    double* __restrict__ gA, double* __restrict__ gB) {
  const int i = blockIdx.x * BLK + threadIdx.x;   // MIDB*BLK == NN
  const float av = (pa[i] + pa[NN + i] + pa[2 * NN + i] + pa[3 * NN + i]) * (1.0f / NN);
  const float bv = (pb[i] + pb[NN + i] + pb[2 * NN + i] + pb[3 * NN + i]) * (1.0f / NN);
  avga[i] = av; avgb[i] = bv;
  double sa = (double)av * (double)w[i];
  double sb = (double)bv * (double)w[i];
#pragma unroll
  for (int off = 32; off >= 1; off >>= 1) {
    sa += __shfl_xor(sa, off);
    sb += __shfl_xor(sb, off);
  }
  __shared__ double lsa[4], lsb[4];
  const int lane = threadIdx.x & 63;
  const int wv = threadIdx.x >> 6;
  if (lane == 0) { lsa[wv] = sa; lsb[wv] = sb; }
  __syncthreads();
  if (threadIdx.x == 0) {
    gA[blockIdx.x] = lsa[0] + lsa[1] + lsa[2] + lsa[3];
    gB[blockIdx.x] = lsb[0] + lsb[1] + lsb[2] + lsb[3];
  }
}

// ---------------------------------------------------------------- K3: pass 2
__global__ __launch_bounds__(BLK) void k_pass2(
    const float* __restrict__ a, const float* __restrict__ b,
    const float* __restrict__ w,
    const float* __restrict__ avga, const float* __restrict__ avgb,
    const double* __restrict__ gA, const double* __restrict__ gB,
    float* __restrict__ pAB, float* __restrict__ pAA, float* __restrict__ pBB) {
  const int lane = threadIdx.x & 63;
  const int wv = threadIdx.x >> 6;
  const int i0 = blockIdx.x * ROWS_PER_BLOCK + wv * RPT;
  const int seg = blockIdx.y;

  // prologue: reduce 32 double partials -> ga, gb (fixed order, deterministic)
  double da = gA[lane & (MIDB - 1)];
  double db = gB[lane & (MIDB - 1)];
#pragma unroll
  for (int off = 16; off >= 1; off >>= 1) {
    da += __shfl_xor(da, off);
    db += __shfl_xor(db, off);
  }
  const float ha = (float)(0.5 * da / NN);   // ga/2
  const float hb = (float)(0.5 * db / NN);

  float ai[RPT], bi[RPT], ra[RPT], rb[RPT];
  float sAB[RPT], sAA[RPT], sBB[RPT];
#pragma unroll
  for (int m = 0; m < RPT; ++m) {
    ai[m] = a[i0 + m]; bi[m] = b[i0 + m];
    ra[m] = avga[i0 + m] - ha;   // adj_i^a
    rb[m] = avgb[i0 + m] - hb;   // adj_i^b
    sAB[m] = 0.f; sAA[m] = 0.f; sBB[m] = 0.f;
  }

  const int jb = seg * SEGC;
  const float4* a4  = (const float4*)(a + jb)    + lane;
  const float4* b4  = (const float4*)(b + jb)    + lane;
  const float4* w4  = (const float4*)(w + jb)    + lane;
  const float4* ca4 = (const float4*)(avga + jb) + lane;
  const float4* cb4 = (const float4*)(avgb + jb) + lane;

  float4 A0 = a4[0], B0 = b4[0], W0 = w4[0], CA0 = ca4[0], CB0 = cb4[0];
#pragma unroll 1
  for (int k = 0; k < ITERS - 1; ++k) {
    const int nx = (k + 1) * 64;
    const float4 A1 = a4[nx], B1 = b4[nx], W1 = w4[nx], CA1 = ca4[nx], CB1 = cb4[nx];
    p2_elem(A0.x, B0.x, W0.x, CA0.x, CB0.x, ha, hb, ai, bi, ra, rb, sAB, sAA, sBB);
    p2_elem(A0.y, B0.y, W0.y, CA0.y, CB0.y, ha, hb, ai, bi, ra, rb, sAB, sAA, sBB);
    p2_elem(A0.z, B0.z, W0.z, CA0.z, CB0.z, ha, hb, ai, bi, ra, rb, sAB, sAA, sBB);
    p2_elem(A0.w, B0.w, W0.w, CA0.w, CB0.w, ha, hb, ai, bi, ra, rb, sAB, sAA, sBB);
    A0 = A1; B0 = B1; W0 = W1; CA0 = CA1; CB0 = CB1;
  }
  p2_elem(A0.x, B0.x, W0.x, CA0.x, CB0.x, ha, hb, ai, bi, ra, rb, sAB, sAA, sBB);
  p2_elem(A0.y, B0.y, W0.y, CA0.y, CB0.y, ha, hb, ai, bi, ra, rb, sAB, sAA, sBB);
  p2_elem(A0.z, B0.z, W0.z, CA0.z, CB0.z, ha, hb, ai, bi, ra, rb, sAB, sAA, sBB);
  p2_elem(A0.w, B0.w, W0.w, CA0.w, CB0.w, ha, hb, ai, bi, ra, rb, sAB, sAA, sBB);

#pragma unroll
  for (int off = 32; off >= 1; off >>= 1) {
#pragma unroll
    for (int m = 0; m < RPT; ++m) {
      sAB[m] += __shfl_xor(sAB[m], off);
      sAA[m] += __shfl_xor(sAA[m], off);
      sBB[m] += __shfl_xor(sBB[m], off);
    }
  }
  if (lane == 0) {
#pragma unroll
    for (int m = 0; m < RPT; ++m) {
      pAB[seg * NN + i0 + m] = sAB[m];
      pAA[seg * NN + i0 + m] = sAA[m];
      pBB[seg * NN + i0 + m] = sBB[m];
    }
  }
}

// ----------------------- K4: assemble rows + abs + weight, per-block partials
__global__ __launch_bounds__(BLK) void k_tail(
    const float* __restrict__ pAB, const float* __restrict__ pAA,
    const float* __restrict__ pBB, const float* __restrict__ w,
    double* __restrict__ fAB, double* __restrict__ fAA, double* __restrict__ fBB) {
  const int i = blockIdx.x * BLK + threadIdx.x;
  const float sab = pAB[i] + pAB[NN + i] + pAB[2 * NN + i] + pAB[3 * NN + i];
  const float saa = pAA[i] + pAA[NN + i] + pAA[2 * NN + i] + pAA[3 * NN + i];
  const float sbb = pBB[i] + pBB[NN + i] + pBB[2 * NN + i] + pBB[3 * NN + i];
  const float wi = w[i];
  double ab = (double)(fabsf(sab) * wi);   // abs of complete row sum
  double aa = (double)(saa * wi);
  double bb = (double)(sbb * wi);
#pragma unroll
  for (int off = 32; off >= 1; off >>= 1) {
    ab += __shfl_xor(ab, off);
    aa += __shfl_xor(aa, off);
    bb += __shfl_xor(bb, off);
  }
  __shared__ double l[3][4];
  const int lane = threadIdx.x & 63;
  const int wv = threadIdx.x >> 6;
  if (lane == 0) { l[0][wv] = ab; l[1][wv] = aa; l[2][wv] = bb; }
  __syncthreads();
  if (threadIdx.x == 0) {
    fAB[blockIdx.x] = l[0][0] + l[0][1] + l[0][2] + l[0][3];
    fAA[blockIdx.x] = l[1][0] + l[1][1] + l[1][2] + l[1][3];
    fBB[blockIdx.x] = l[2][0] + l[2][1] + l[2][2] + l[2][3];
  }
}

// ---------------------------------------------------------------- K5: finalize
__global__ __launch_bounds__(64) void k_fin(
    const double* __restrict__ fAB, const double* __restrict__ fAA,
    const double* __restrict__ fBB, const int* __restrict__ powerPtr,
    float* __restrict__ out) {
  const int lane = threadIdx.x;
  double ab = fAB[lane & (MIDB - 1)];
  double aa = fAA[lane & (MIDB - 1)];
  double bb = fBB[lane & (MIDB - 1)];
#pragma unroll
  for (int off = 16; off >= 1; off >>= 1) {
    ab += __shfl_xor(ab, off);
    aa += __shfl_xor(aa, off);
    bb += __shfl_xor(bb, off);
  }
  if (lane == 0) {
    const double n2 = (double)NN * (double)NN;
    const double num = ab / n2;
    const double mAA = aa / n2;
    const double mBB = bb / n2;
    const double den = fabs(mAA * mBB);
    const int p = powerPtr[0];
    double d;
    if (p == 1) {
      d = num / sqrt(den + 1e-12);
    } else if (p == 2) {
      d = (num * num) / (den + 1e-12);
    } else {
      d = pow(num / sqrt(mAA * mBB) + 1e-12, (double)p);
    }
    if (isnan(d)) d = 0.0;
    if (d < 0.0) d = 0.0;
    out[0] = (float)d;
  }
}

// -------------------------------------------------------------------- launcher
extern "C" void kernel_launch(void* const* d_in, const int* in_sizes, int n_in,
                              void* d_out, int out_size, void* d_ws, size_t ws_size,
                              hipStream_t stream) {
  const float* a = (const float*)d_in[0];
  const float* b = (const float*)d_in[1];
  const float* w = (const float*)d_in[2];
  const int* power = (const int*)d_in[3];
  float* out = (float*)d_out;

  float* ws = (float*)d_ws;
  float* pa   = ws;                  // [4N]
  float* pb   = pa + 4 * NN;         // [4N]
  float* pAB  = pb + 4 * NN;         // [4N]
  float* pAA  = pAB + 4 * NN;        // [4N]
  float* pBB  = pAA + 4 * NN;        // [4N]
  float* avga = pBB + 4 * NN;        // [N]
  float* avgb = avga + NN;           // [N]
  double* dbl = (double*)(avgb + NN);  // 8B-aligned (22N floats = 720896 B)
  double* gA  = dbl;                 // [32]
  double* gB  = gA + MIDB;           // [32]
  double* fAB = gB + MIDB;           // [32]
  double* fAA = fAB + MIDB;          // [32]
  double* fBB = fAA + MIDB;          // [32]

  const dim3 grid(GRIDX, CSPLIT);
  k_pass1<<<grid, BLK, 0, stream>>>(a, b, w, pa, pb);
  k_mid<<<MIDB, BLK, 0, stream>>>(pa, pb, w, avga, avgb, gA, gB);
  k_pass2<<<grid, BLK, 0, stream>>>(a, b, w, avga, avgb, gA, gB, pAB, pAA, pBB);
  k_tail<<<MIDB, BLK, 0, stream>>>(pAB, pAA, pBB, w, fAB, fAA, fBB);
  k_fin<<<1, 64, 0, stream>>>(fAB, fAA, fBB, power, out);
}